// Round 1
// baseline (57.647 us; speedup 1.0000x reference)
//
#include <hip/hip_runtime.h>

// Algebraic reduction of the reference:
//   s = sum_i m_embeddings[idx[i]]           [256]
//   p = sum_i pretrained_weight[idx[i]]      [256]
//   out[c] = p[c] + dot(W[c,:], s) + N * bias[c]
//
// Kernel 1: gather-sum of 2*N rows (1 KB each) -> d_ws accumulators (memory-bound).
// Kernel 2: 256x256 matvec + combine (negligible).

__global__ __launch_bounds__(256) void gather_sum_kernel(
    const int* __restrict__ idx,
    const float* __restrict__ memb,   // [VOCAB, 256]
    const float* __restrict__ pre,    // [VOCAB, 256]
    float* __restrict__ gS,           // [256] accumulators in d_ws
    float* __restrict__ gP,           // [256]
    int n)
{
    const int lane = threadIdx.x & 63;
    const int wave = threadIdx.x >> 6;                 // 0..3
    const int globalWave = blockIdx.x * 4 + wave;
    const int totalWaves = gridDim.x * 4;

    float4 accS = make_float4(0.f, 0.f, 0.f, 0.f);
    float4 accP = make_float4(0.f, 0.f, 0.f, 0.f);

    // One wave per index: 64 lanes x float4 = one full 1KB row per vector load.
    for (int i = globalWave; i < n; i += totalWaves) {
        const int r = idx[i];                          // broadcast load (same addr all lanes)
        const float4* mrow = reinterpret_cast<const float4*>(memb + (size_t)r * 256);
        const float4* prow = reinterpret_cast<const float4*>(pre  + (size_t)r * 256);
        const float4 a = mrow[lane];
        const float4 b = prow[lane];
        accS.x += a.x; accS.y += a.y; accS.z += a.z; accS.w += a.w;
        accP.x += b.x; accP.y += b.y; accP.z += b.z; accP.w += b.w;
    }

    // Block-level reduction: lane l of each wave owns channels [4l, 4l+4).
    __shared__ float sS[256];
    __shared__ float sP[256];
    sS[threadIdx.x] = 0.f;
    sP[threadIdx.x] = 0.f;
    __syncthreads();

    const int c = lane * 4;
    atomicAdd(&sS[c + 0], accS.x);
    atomicAdd(&sS[c + 1], accS.y);
    atomicAdd(&sS[c + 2], accS.z);
    atomicAdd(&sS[c + 3], accS.w);
    atomicAdd(&sP[c + 0], accP.x);
    atomicAdd(&sP[c + 1], accP.y);
    atomicAdd(&sP[c + 2], accP.z);
    atomicAdd(&sP[c + 3], accP.w);
    __syncthreads();

    // One global atomic per channel per block (device-scope by default).
    atomicAdd(&gS[threadIdx.x], sS[threadIdx.x]);
    atomicAdd(&gP[threadIdx.x], sP[threadIdx.x]);
}

__global__ __launch_bounds__(256) void finish_kernel(
    const float* __restrict__ gS,
    const float* __restrict__ gP,
    const float* __restrict__ W,      // [256, 256] row-major: W[c][k]
    const float* __restrict__ bias,   // [256]
    float* __restrict__ out,          // [256]
    float nf)
{
    const int c = blockIdx.x;          // output channel
    const int t = threadIdx.x;         // 0..255

    float v = W[(size_t)c * 256 + t] * gS[t];

    // Wave reduce (64 lanes).
    for (int off = 32; off > 0; off >>= 1)
        v += __shfl_down(v, off, 64);

    __shared__ float part[4];
    if ((t & 63) == 0) part[t >> 6] = v;
    __syncthreads();

    if (t == 0) {
        const float s = part[0] + part[1] + part[2] + part[3];
        out[c] = s + gP[c] + nf * bias[c];
    }
}

extern "C" void kernel_launch(void* const* d_in, const int* in_sizes, int n_in,
                              void* d_out, int out_size, void* d_ws, size_t ws_size,
                              hipStream_t stream)
{
    const int*   idx  = (const int*)d_in[0];     // medicine_it      [N]
    const float* memb = (const float*)d_in[1];   // m_embeddings     [VOCAB,256]
    const float* pre  = (const float*)d_in[2];   // pretrained_weight[VOCAB,256]
    const float* W    = (const float*)d_in[3];   // W                [256,256]
    const float* bias = (const float*)d_in[4];   // bias             [256]
    float* out = (float*)d_out;                  // [1,1,256] -> 256 floats

    const int n = in_sizes[0];

    float* gS = (float*)d_ws;        // [256]
    float* gP = gS + 256;            // [256]

    // Zero accumulators every call (harness does not re-poison between replays).
    hipMemsetAsync(d_ws, 0, 512 * sizeof(float), stream);

    gather_sum_kernel<<<512, 256, 0, stream>>>(idx, memb, pre, gS, gP, n);
    finish_kernel<<<256, 256, 0, stream>>>(gS, gP, W, bias, out, (float)n);
}